// Round 3
// baseline (1740.485 us; speedup 1.0000x reference)
//
#include <hip/hip_runtime.h>
#include <math.h>

#define MM 400
#define MM1 401
#define CC 8
#define WW 128
#define LL 50
#define DD 300
#define RR 3
#define HH 100
#define TOPN 25
#define NEGC 1e10f
#define LAMC 0.3f
#define NLOOPS 10
#define INV_SQRT_D 0.05773502691896258f

// ---------------- workspace layout (floats) ----------------
constexpr long OFF_BASE  = 0;                                              // [M1][M1][C][C] ee+local
constexpr long OFF_EV    = OFF_BASE + (long)MM1 * CC * MM1 * CC;           // [M1*C][D] entity vecs (+pad row)
constexpr long OFF_CTX   = OFF_EV + (long)MM1 * CC * DD;                   // [M1][D] ctx_vecs (+pad row)
constexpr long OFF_WTS   = OFF_CTX + (((long)MM1 * DD + 3) / 4) * 4;       // [R][M1][M1] weights
constexpr long OFF_RCC   = OFF_WTS + (((long)RR * MM1 * MM1 + 3) / 4) * 4; // [R][M1][M1] rcc -> probs
constexpr long OFF_BOW   = OFF_RCC + (((long)RR * MM1 * MM1 + 3) / 4) * 4; // [M][900]
constexpr long OFF_LOC   = OFF_BOW + (long)MM * 3 * DD;                    // [M1][C] local
constexpr long OFF_PREVA = OFF_LOC + (long)MM1 * CC;                       // [M1][C][M1] msgs buf A
constexpr long OFF_PREVB = OFF_PREVA + (long)MM1 * CC * MM1;               // [M1][C][M1] msgs buf B
constexpr long OFF_RS    = OFF_PREVB + (long)MM1 * CC * MM1;               // [NLOOPS+1][M1*C] rowsums
// total = OFF_RS + 11*3208 ~= 15.31M floats ~= 58.4 MB

// ---------------- init: zero prevA + RS chain, write pad rows ----------------
__global__ __launch_bounds__(256) void k_init(float* __restrict__ ws,
                                              const float* __restrict__ pad_ent,
                                              const float* __restrict__ pad_ctx) {
  long nprev = (long)MM1 * CC * MM1;
  long nz = nprev + (long)(NLOOPS + 1) * MM1 * CC;
  long stride = (long)gridDim.x * blockDim.x;
  long gid = (long)blockIdx.x * blockDim.x + threadIdx.x;
  for (long i = gid; i < nz; i += stride) {
    if (i < nprev) ws[OFF_PREVA + i] = 0.f;
    else ws[OFF_RS + (i - nprev)] = 0.f;
  }
  if (gid < DD) {
    ws[OFF_CTX + (long)MM * DD + gid] = pad_ctx[gid];
    float pe = pad_ent[gid];
    for (int c = 0; c < CC; ++c) ws[OFF_EV + ((long)MM * CC + c) * DD + gid] = pe;
  }
  if (gid < CC) ws[OFF_LOC + (long)MM * CC + gid] = 0.f;
}

// ---------------- gather entity vectors ----------------
__global__ __launch_bounds__(64) void k_ev(float* __restrict__ ws,
                                           const int* __restrict__ eids,
                                           const float* __restrict__ eemb) {
  int mc = blockIdx.x;  // 0..M*C-1
  long row = eids[mc];
  const float* src = eemb + row * DD;
  float* dst = ws + OFF_EV + (long)mc * DD;
  for (int d = threadIdx.x; d < DD; d += 64) dst[d] = src[d];
}

// ---------------- attention -> top25 -> ctx -> local, one block per m ----------------
__global__ __launch_bounds__(256) void k_att(float* __restrict__ ws,
    const int* __restrict__ token_ids, const float* __restrict__ tok_mask,
    const float* __restrict__ word_emb, const float* __restrict__ amd,
    const float* __restrict__ tsmd, const float* __restrict__ emask) {
  __shared__ float evA[CC * DD];   // ev * att_mat_diag
  __shared__ float evR[CC * DD];   // raw ev
  __shared__ float tokatt[WW];
  __shared__ float topv[TOPN];
  __shared__ int   topi[TOPN];
  __shared__ float pP[TOPN];
  __shared__ long  rowoff[TOPN];
  __shared__ float ctxL[DD];
  int m = blockIdx.x, tid = threadIdx.x;
  int wave = tid >> 6, lane = tid & 63;
  for (int i = tid; i < CC * DD; i += 256) {
    float v = ws[OFF_EV + (long)m * CC * DD + i];
    evR[i] = v;
    evA[i] = v * amd[i % DD];
  }
  __syncthreads();
  // att[c][w] then masked max over c -> tokatt[w]; one wave per w
  for (int w = wave; w < WW; w += 4) {
    float acc[CC];
#pragma unroll
    for (int c = 0; c < CC; ++c) acc[c] = 0.f;
    const float* trow = word_emb + (long)token_ids[m * WW + w] * DD;
    for (int d = lane; d < DD; d += 64) {
      float t = trow[d];
#pragma unroll
      for (int c = 0; c < CC; ++c) acc[c] = fmaf(t, evA[c * DD + d], acc[c]);
    }
#pragma unroll
    for (int c = 0; c < CC; ++c) {
      float v = acc[c];
      for (int off = 32; off > 0; off >>= 1) v += __shfl_down(v, off);
      acc[c] = v;
    }
    if (lane == 0) {
      float tmv = tok_mask[m * WW + w];
      float mx = -INFINITY;
#pragma unroll
      for (int c = 0; c < CC; ++c) mx = fmaxf(mx, acc[c] * tmv + (tmv - 1.f) * NEGC);
      tokatt[w] = mx;
    }
  }
  __syncthreads();
  // top-25 (lower index wins ties), registers + shuffles only (wave 0)
  if (wave == 0) {
    float v0 = tokatt[lane], v1 = tokatt[lane + 64];
    for (int it = 0; it < TOPN; ++it) {
      float bv; int bi;
      if (v1 > v0) { bv = v1; bi = lane + 64; } else { bv = v0; bi = lane; }
      for (int off = 32; off > 0; off >>= 1) {
        float ov = __shfl_down(bv, off);
        int   oi = __shfl_down(bi, off);
        if (ov > bv || (ov == bv && oi < bi)) { bv = ov; bi = oi; }
      }
      bv = __shfl(bv, 0);
      bi = __shfl(bi, 0);
      if (lane == 0) { topv[it] = bv; topi[it] = bi; }
      if (bi == lane) v0 = -INFINITY;
      if (bi == lane + 64) v1 = -INFINITY;
    }
  }
  __syncthreads();
  if (tid == 0) {
    float mx = -INFINITY;
    for (int i = 0; i < TOPN; ++i) mx = fmaxf(mx, topv[i]);
    float s = 0.f;
    for (int i = 0; i < TOPN; ++i) { float e = expf(topv[i] - mx); pP[i] = e; s += e; }
    float inv = 1.f / s;
    float s2 = 0.f;
    for (int i = 0; i < TOPN; ++i) { pP[i] *= inv; s2 += pP[i]; }
    float inv2 = 1.f / s2;   // reference normalizes twice
    for (int i = 0; i < TOPN; ++i) { pP[i] *= inv2; rowoff[i] = (long)token_ids[m * WW + topi[i]] * DD; }
  }
  __syncthreads();
  for (int d = tid; d < DD; d += 256) {
    float s = 0.f;
#pragma unroll
    for (int i = 0; i < TOPN; ++i) s = fmaf(word_emb[rowoff[i] + d], pP[i], s);
    ctxL[d] = s * tsmd[d];
  }
  __syncthreads();
  for (int c = wave; c < CC; c += 4) {
    float acc = 0.f;
    for (int d = lane; d < DD; d += 64) acc = fmaf(evR[c * DD + d], ctxL[d], acc);
    for (int off = 32; off > 0; off >>= 1) acc += __shfl_down(acc, off);
    if (lane == 0) {
      float em = emask[m * CC + c];
      ws[OFF_LOC + m * CC + c] = acc * em + (em - 1.f) * NEGC;
    }
  }
}

// ---------------- bow (segments: l, m, r) ----------------
__global__ __launch_bounds__(256) void k_bow(float* __restrict__ ws,
    const int* __restrict__ lid, const float* __restrict__ lmask,
    const int* __restrict__ mid, const float* __restrict__ mmask,
    const int* __restrict__ rid, const float* __restrict__ rmask,
    const float* __restrict__ snd) {
  __shared__ float mk[LL];
  __shared__ long  ro[LL];
  int m = blockIdx.x, tid = threadIdx.x;
  const int* ids[3] = { lid, mid, rid };
  const float* msk[3] = { lmask, mmask, rmask };
  for (int seg = 0; seg < 3; ++seg) {
    if (tid < LL) {
      mk[tid] = msk[seg][m * LL + tid];
      ro[tid] = (long)ids[seg][m * LL + tid] * DD;
    }
    __syncthreads();
    float denom = 1e-5f;
    for (int l = 0; l < LL; ++l) denom += mk[l];
    float inv = 1.f / denom;
    for (int d = tid; d < DD; d += 256) {
      float s = 0.f;
      for (int l = 0; l < LL; ++l) s = fmaf(snd[ro[l] + d], mk[l], s);
      ws[OFF_BOW + (long)m * (3 * DD) + seg * DD + d] = s * inv;
    }
    __syncthreads();
  }
}

// ---------------- ctx_vecs = tanh(bow @ ctx_W + b) ----------------
__global__ __launch_bounds__(256) void k_ctx(float* __restrict__ ws,
    const float* __restrict__ ctx_W, const float* __restrict__ ctx_b) {
  __shared__ float bw[3 * DD];
  int m = blockIdx.x, tid = threadIdx.x;
  for (int i = tid; i < 3 * DD; i += 256) bw[i] = ws[OFF_BOW + (long)m * (3 * DD) + i];
  __syncthreads();
  for (int d = tid; d < DD; d += 256) {
    float acc = ctx_b[d];
    for (int j = 0; j < 3 * DD; ++j) acc = fmaf(bw[j], ctx_W[(long)j * DD + d], acc);
    ws[OFF_CTX + (long)m * DD + d] = tanhf(acc);
  }
}

// ---------------- rcc[r][m][n] masked+scaled ----------------
__global__ __launch_bounds__(256) void k_rcc(float* __restrict__ ws, const float* __restrict__ ew) {
  int m = blockIdx.x, r = blockIdx.y;
  __shared__ float cm[DD];
  int tid = threadIdx.x, wave = tid >> 6, lane = tid & 63;
  for (int d = tid; d < DD; d += 256) cm[d] = ws[OFF_CTX + (long)m * DD + d] * ew[r * DD + d];
  __syncthreads();
  for (int n = wave; n < MM1; n += 4) {
    float acc = 0.f;
    const float* cn = ws + OFF_CTX + (long)n * DD;
    for (int d = lane; d < DD; d += 64) acc = fmaf(cm[d], cn[d], acc);
    for (int off = 32; off > 0; off >>= 1) acc += __shfl_down(acc, off);
    if (lane == 0) {
      int ad = m > n ? m - n : n - m;
      int d2 = (ad == 1) ? -1 : ad;
      if (d2 > 1 && d2 <= 1000) d2 = -1;
      if (d2 > 1000) d2 = 0;
      float dist = (float)(-d2);
      float v = acc + (1.f - dist) * (-NEGC) + (m == n ? -NEGC : 0.f);
      ws[OFF_RCC + ((long)r * MM1 + m) * MM1 + n] = v * INV_SQRT_D;
    }
  }
}

// ---------------- softmax over n, in place ----------------
__global__ __launch_bounds__(256) void k_sm(float* __restrict__ ws) {
  int m = blockIdx.x, r = blockIdx.y;
  float* row = ws + OFF_RCC + ((long)r * MM1 + m) * MM1;
  __shared__ float redm[4], reds[4];
  int tid = threadIdx.x, wave = tid >> 6, lane = tid & 63;
  float mx = -INFINITY;
  for (int n = tid; n < MM1; n += 256) mx = fmaxf(mx, row[n]);
  for (int off = 32; off > 0; off >>= 1) mx = fmaxf(mx, __shfl_xor(mx, off));
  if (lane == 0) redm[wave] = mx;
  __syncthreads();
  mx = fmaxf(fmaxf(redm[0], redm[1]), fmaxf(redm[2], redm[3]));
  float s = 0.f;
  for (int n = tid; n < MM1; n += 256) s += expf(row[n] - mx);
  for (int off = 32; off > 0; off >>= 1) s += __shfl_xor(s, off);
  if (lane == 0) reds[wave] = s;
  __syncthreads();
  s = reds[0] + reds[1] + reds[2] + reds[3];
  float inv = 1.f / s;
  for (int n = tid; n < MM1; n += 256) row[n] = expf(row[n] - mx) * inv;
}

// ---------------- weights = probs + probs^T ----------------
__global__ __launch_bounds__(256) void k_wts(float* __restrict__ ws) {
  long tot = (long)RR * MM1 * MM1;
  long stride = (long)gridDim.x * blockDim.x;
  for (long i = (long)blockIdx.x * blockDim.x + threadIdx.x; i < tot; i += stride) {
    long r = i / ((long)MM1 * MM1);
    long rem = i % ((long)MM1 * MM1);
    long mm = rem / MM1, nn = rem % MM1;
    ws[OFF_WTS + i] = ws[OFF_RCC + i] + ws[OFF_RCC + (r * MM1 + nn) * MM1 + mm];
  }
}

// ---------------- base[m][n][c][k] = ee + local[n][k] ----------------
// ee = (1/R) * ( emask[n,k] * sum_d q[d]*evm[c,d]*evn[k,d] + (emask-1)*NEG*wsum )
// with q[d] = sum_r wts[r,m,n]*rel[r,d]
__global__ __launch_bounds__(256) void k_base(float* __restrict__ ws,
    const float* __restrict__ rel, const float* __restrict__ emaskIn) {
  int m = blockIdx.x;
  int n0 = blockIdx.y * 4;
  __shared__ alignas(16) float evm[CC * DD];
  __shared__ alignas(16) float evn[4 * CC * DD];
  __shared__ alignas(16) float qq[4 * DD];
  __shared__ float wL[12];
  __shared__ float wsumL[4], emL[32], locL[32];
  int tid = threadIdx.x;
  for (int i = tid; i < CC * DD; i += 256) evm[i] = ws[OFF_EV + (long)m * CC * DD + i];
  for (int i = tid; i < 4 * CC * DD; i += 256) {
    int nl = i / (CC * DD);
    int rest = i % (CC * DD);
    int n = n0 + nl;
    evn[i] = (n < MM1) ? ws[OFF_EV + (long)n * CC * DD + rest] : 0.f;
  }
  if (tid < 12) {
    int r = tid / 4, nl = tid % 4;
    int n = n0 + nl;
    wL[tid] = (n < MM1) ? ws[OFF_WTS + ((long)r * MM1 + m) * MM1 + n] : 0.f;
  }
  if (tid < 32) {
    int nl = tid / 8, k = tid % 8;
    int n = n0 + nl;
    float em = 0.f, lc = 0.f;
    if (n < MM1) {
      em = (n < MM) ? emaskIn[n * CC + k] : (k == 0 ? 1.f : 0.f);
      lc = ws[OFF_LOC + n * CC + k];
    }
    emL[tid] = em;
    locL[tid] = lc;
  }
  __syncthreads();
  if (tid < 4) wsumL[tid] = wL[tid] + wL[4 + tid] + wL[8 + tid];
  for (int i = tid; i < 4 * DD; i += 256) {
    int nl = i / DD, d = i % DD;
    qq[i] = wL[nl] * rel[d] + wL[4 + nl] * rel[DD + d] + wL[8 + nl] * rel[2 * DD + d];
  }
  __syncthreads();
  int nl = tid >> 6, c = (tid >> 3) & 7, k = tid & 7;
  int n = n0 + nl;
  if (n < MM1) {
    const float4* a  = (const float4*)(evm + c * DD);
    const float4* b  = (const float4*)(evn + (nl * CC + k) * DD);
    const float4* qv = (const float4*)(qq + nl * DD);
    float acc = 0.f;
#pragma unroll 5
    for (int i = 0; i < DD / 4; ++i) {
      float4 av = a[i], bv = b[i], q4 = qv[i];
      acc = fmaf(q4.x * av.x, bv.x, acc);
      acc = fmaf(q4.y * av.y, bv.y, acc);
      acc = fmaf(q4.z * av.z, bv.z, acc);
      acc = fmaf(q4.w * av.w, bv.w, acc);
    }
    float em = emL[nl * 8 + k];
    float val = (em * acc + (em - 1.f) * NEGC * wsumL[nl]) * (1.f / 3.f) + locL[nl * 8 + k];
    ws[OFF_BASE + (((long)m * MM1 + n) * CC + c) * CC + k] = val;
  }
}

// ---------------- one message-passing iteration ----------------
__global__ __launch_bounds__(256) void k_loop(float* __restrict__ ws,
    const float* __restrict__ prev, float* __restrict__ nxt,
    const float* __restrict__ rs, float* __restrict__ rsnext) {
  int m = blockIdx.x;
  int n0 = blockIdx.y * 4;
  int tid = threadIdx.x;
  int nl = tid >> 6, c = (tid >> 3) & 7, k = tid & 7;
  int n = n0 + nl;
  __shared__ float partial[4][8];
  bool valid = (n < MM1);
  float newv = 0.f;
  if (valid) {
    float b = ws[OFF_BASE + (((long)m * MM1 + n) * CC + c) * CC + k];
    float v = b + rs[n * CC + k] - prev[((long)n * CC + k) * MM1 + m];
    // max over k (lane bits 0..2)
    for (int off = 1; off < 8; off <<= 1) v = fmaxf(v, __shfl_xor(v, off));
    // softmax over c (lane bits 3..5)
    float mx = v;
    for (int off = 8; off < 64; off <<= 1) mx = fmaxf(mx, __shfl_xor(mx, off));
    float e = expf(v - mx);
    float s = e;
    for (int off = 8; off < 64; off <<= 1) s += __shfl_xor(s, off);
    float sm = e / s;
    float pv = prev[((long)m * CC + c) * MM1 + n];
    newv = logf(sm * LAMC + expf(pv) * (1.f - LAMC));
    if (k == 0) nxt[((long)m * CC + c) * MM1 + n] = newv;
  }
  if (k == 0) partial[nl][c] = valid ? newv : 0.f;
  __syncthreads();
  if (tid < CC) {
    float s = partial[0][tid] + partial[1][tid] + partial[2][tid] + partial[3][tid];
    atomicAdd(&rsnext[m * CC + tid], s);
  }
}

// ---------------- final: ent_scores softmax + scoring MLP ----------------
__global__ __launch_bounds__(128) void k_final(float* __restrict__ ws,
    const float* __restrict__ pem_in, const float* __restrict__ W1,
    const float* __restrict__ b1, const float* __restrict__ W2,
    const float* __restrict__ b2, float* __restrict__ out,
    const float* __restrict__ msgs, const float* __restrict__ rs10) {
  int m = blockIdx.x, tid = threadIdx.x;
  __shared__ float es[CC];
  __shared__ float sc[CC];
  if (tid < CC) {
    es[tid] = ws[OFF_LOC + m * CC + tid] + rs10[m * CC + tid]
            - msgs[((long)m * CC + tid) * MM1 + m];
  }
  __syncthreads();
  if (tid == 0) {
    float mx = -INFINITY;
    for (int c = 0; c < CC; ++c) mx = fmaxf(mx, es[c]);
    float s = 0.f;
    for (int c = 0; c < CC; ++c) { float e = expf(es[c] - mx); es[c] = e; s += e; }
    float inv = 1.f / s;
    for (int c = 0; c < CC; ++c) { es[c] *= inv; sc[c] = b2[0]; }
  }
  __syncthreads();
  for (int idx = tid; idx < CC * HH; idx += 128) {
    int c = idx / HH, j = idx % HH;
    float pem = (m < MM) ? pem_in[m * CC + c] : (c == 0 ? 1.f : 0.f);
    float i0 = es[c];
    float i1 = logf(pem + 1e-20f);
    float h = fmaxf(i0 * W1[j] + i1 * W1[HH + j] + b1[j], 0.f);
    atomicAdd(&sc[c], h * W2[j]);
  }
  __syncthreads();
  if (tid < CC) {
    out[(long)MM * CC + m * CC + tid] = es[tid];       // ent_scores (401x8) at offset 3200
    if (m < MM) out[m * CC + tid] = sc[tid];           // scores[:-1] (400x8)
  }
}

extern "C" void kernel_launch(void* const* d_in, const int* in_sizes, int n_in,
                              void* d_out, int out_size, void* d_ws, size_t ws_size,
                              hipStream_t stream) {
  (void)in_sizes; (void)n_in; (void)out_size; (void)ws_size;
  const int*   token_ids  = (const int*)d_in[0];
  const float* tok_mask   = (const float*)d_in[1];
  const int*   entity_ids = (const int*)d_in[2];
  const float* entity_msk = (const float*)d_in[3];
  const float* p_e_m      = (const float*)d_in[4];
  const int*   s_lid      = (const int*)d_in[5];
  const float* s_lmask    = (const float*)d_in[6];
  const int*   s_rid      = (const int*)d_in[7];
  const float* s_rmask    = (const float*)d_in[8];
  const int*   s_mid      = (const int*)d_in[9];
  const float* s_mmask    = (const float*)d_in[10];
  const float* word_emb   = (const float*)d_in[11];
  const float* entity_emb = (const float*)d_in[12];
  const float* snd_emb    = (const float*)d_in[13];
  const float* amd        = (const float*)d_in[14];
  const float* tsmd       = (const float*)d_in[15];
  const float* rel        = (const float*)d_in[16];
  const float* ew         = (const float*)d_in[17];
  const float* pad_ent    = (const float*)d_in[18];
  const float* pad_ctx    = (const float*)d_in[19];
  const float* ctx_W      = (const float*)d_in[20];
  const float* ctx_b      = (const float*)d_in[21];
  const float* W1         = (const float*)d_in[22];
  const float* b1         = (const float*)d_in[23];
  const float* W2         = (const float*)d_in[24];
  const float* b2         = (const float*)d_in[25];
  float* ws  = (float*)d_ws;
  float* out = (float*)d_out;

  k_init<<<512, 256, 0, stream>>>(ws, pad_ent, pad_ctx);
  k_ev<<<MM * CC, 64, 0, stream>>>(ws, entity_ids, entity_emb);
  k_att<<<MM, 256, 0, stream>>>(ws, token_ids, tok_mask, word_emb, amd, tsmd, entity_msk);
  k_bow<<<MM, 256, 0, stream>>>(ws, s_lid, s_lmask, s_mid, s_mmask, s_rid, s_rmask, snd_emb);
  k_ctx<<<MM, 256, 0, stream>>>(ws, ctx_W, ctx_b);
  k_rcc<<<dim3(MM1, RR), 256, 0, stream>>>(ws, ew);
  k_sm<<<dim3(MM1, RR), 256, 0, stream>>>(ws);
  k_wts<<<256, 256, 0, stream>>>(ws);
  k_base<<<dim3(MM1, (MM1 + 3) / 4), 256, 0, stream>>>(ws, rel, entity_msk);

  float* A = ws + OFF_PREVA;
  float* B = ws + OFF_PREVB;
  for (int t = 0; t < NLOOPS; ++t) {
    const float* p = (t & 1) ? B : A;
    float* nx      = (t & 1) ? A : B;
    k_loop<<<dim3(MM1, (MM1 + 3) / 4), 256, 0, stream>>>(
        ws, p, nx, ws + OFF_RS + (long)t * MM1 * CC, ws + OFF_RS + (long)(t + 1) * MM1 * CC);
  }
  // after 10 iters (t=9 odd: B->A), final msgs in A; RS[10] holds its rowsums
  k_final<<<MM1, 128, 0, stream>>>(ws, p_e_m, W1, b1, W2, b2, out, A,
                                   ws + OFF_RS + (long)NLOOPS * MM1 * CC);
}